// Round 2
// baseline (850.953 us; speedup 1.0000x reference)
//
#include <hip/hip_runtime.h>

#define HSZ  2048
#define NL   8
#define NBLK 1024     // = 256 CUs x 4 blocks/CU (exact-fit co-residency)
#define NTHR 512      // 8 waves/block -> 32 waves/CU

// Device-scope grid barrier. Each barrier counter is used exactly once per
// kernel call; counters are zeroed by hipMemsetAsync before launch.
__device__ __forceinline__ void grid_sync(unsigned* cnt) {
    __syncthreads();
    if (threadIdx.x == 0) {
        __threadfence();  // make this block's h-store visible before arrival
        __hip_atomic_fetch_add(cnt, 1u, __ATOMIC_RELEASE, __HIP_MEMORY_SCOPE_AGENT);
        while (__hip_atomic_load(cnt, __ATOMIC_RELAXED, __HIP_MEMORY_SCOPE_AGENT) < NBLK)
            __builtin_amdgcn_s_sleep(2);
        // one acquire to pull in all released stores (L1/L2 invalidate)
        (void)__hip_atomic_load(cnt, __ATOMIC_ACQUIRE, __HIP_MEMORY_SCOPE_AGENT);
    }
    __syncthreads();
}

// Wave w (0..7) of block b owns gate (w&3) of output j = b + NBLK*(w>>2).
// Per layer: 16-float4-per-lane dot products (w_ih row . in) + (w_hh row . h0),
// 64-lane shuffle reduce, LDS-combine 4 gates, 2 threads do the cell math.
__global__ __launch_bounds__(NTHR, 8) void lstm_fused_kernel(
    const float* __restrict__ x,
    const float* __restrict__ w_ih,   // [L, 4H, H]
    const float* __restrict__ w_hh,   // [L, 4H, H]
    const float* __restrict__ b_ih,   // [L, 4H]
    const float* __restrict__ b_hh,   // [L, 4H]
    const float* __restrict__ h0,     // [L, H]
    const float* __restrict__ c0,     // [L, H]
    float* __restrict__ out,          // [H]
    float* __restrict__ buf0,
    float* __restrict__ buf1,
    unsigned* __restrict__ bar_cnt)   // [NL-1], pre-zeroed
{
    const int wave = threadIdx.x >> 6;         // 0..7
    const int lane = threadIdx.x & 63;
    const int gate = wave & 3;
    const int j    = blockIdx.x + NBLK * (wave >> 2);  // 0..2047
    const int row  = gate * HSZ + j;

    __shared__ float gates[2][4];

    const float* cur = x;
    for (int l = 0; l < NL; ++l) {
        const float4* __restrict__ wih4 =
            (const float4*)(w_ih + (size_t)l * 4 * HSZ * HSZ + (size_t)row * HSZ);
        const float4* __restrict__ whh4 =
            (const float4*)(w_hh + (size_t)l * 4 * HSZ * HSZ + (size_t)row * HSZ);
        const float4* __restrict__ in4 = (const float4*)cur;
        const float4* __restrict__ h4  = (const float4*)(h0 + (size_t)l * HSZ);

        float acc = 0.f;
        #pragma unroll
        for (int it = 0; it < 8; ++it) {
            const int k = it * 64 + lane;
            float4 a  = wih4[k];
            float4 xv = in4[k];
            acc += a.x * xv.x + a.y * xv.y + a.z * xv.z + a.w * xv.w;
        }
        #pragma unroll
        for (int it = 0; it < 8; ++it) {
            const int k = it * 64 + lane;
            float4 b  = whh4[k];
            float4 hv = h4[k];
            acc += b.x * hv.x + b.y * hv.y + b.z * hv.z + b.w * hv.w;
        }

        #pragma unroll
        for (int off = 32; off > 0; off >>= 1)
            acc += __shfl_down(acc, off, 64);

        if (lane == 0)
            gates[wave >> 2][gate] = acc + b_ih[(size_t)l * 4 * HSZ + row]
                                         + b_hh[(size_t)l * 4 * HSZ + row];
        __syncthreads();

        float* obuf = (l == NL - 1) ? out : ((l & 1) ? buf1 : buf0);
        if (threadIdx.x < 2) {
            const int jj = blockIdx.x + (int)threadIdx.x * NBLK;
            const float gi = gates[threadIdx.x][0];
            const float gf = gates[threadIdx.x][1];
            const float gg = gates[threadIdx.x][2];
            const float go = gates[threadIdx.x][3];
            const float si = 1.f / (1.f + __expf(-gi));
            const float sf = 1.f / (1.f + __expf(-gf));
            const float so = 1.f / (1.f + __expf(-go));
            const float tg = tanhf(gg);
            const float c_new = sf * c0[(size_t)l * HSZ + jj] + si * tg;
            float h = so * tanhf(c_new);
            if (l < NL - 1) h = tanhf(h);
            obuf[jj] = h;
        }

        if (l < NL - 1) {
            grid_sync(bar_cnt + l);
            cur = obuf;
        }
    }
}

extern "C" void kernel_launch(void* const* d_in, const int* in_sizes, int n_in,
                              void* d_out, int out_size, void* d_ws, size_t ws_size,
                              hipStream_t stream) {
    const float* x    = (const float*)d_in[0];
    const float* w_ih = (const float*)d_in[1];
    const float* w_hh = (const float*)d_in[2];
    const float* b_ih = (const float*)d_in[3];
    const float* b_hh = (const float*)d_in[4];
    const float* h0   = (const float*)d_in[5];
    const float* c0   = (const float*)d_in[6];
    float* out = (float*)d_out;

    // ws layout: [0,256) barrier counters, then buf0, buf1
    unsigned* bar_cnt = (unsigned*)d_ws;
    float* buf0 = (float*)((char*)d_ws + 256);
    float* buf1 = buf0 + HSZ;

    hipMemsetAsync(bar_cnt, 0, (NL - 1) * sizeof(unsigned), stream);
    lstm_fused_kernel<<<NBLK, NTHR, 0, stream>>>(
        x, w_ih, w_hh, b_ih, b_hh, h0, c0, out, buf0, buf1, bar_cnt);
}

// Round 3
// 398.085 us; speedup vs baseline: 2.1376x; 2.1376x over previous
//
#include <hip/hip_runtime.h>

#define HSZ   2048
#define NL    8
#define NBLK  512          // 2 blocks/CU on 256 CUs (exact-fit co-residency)
#define NTHR  1024         // 16 waves/block -> 32 waves/CU
#define NGRP  64           // barrier groups
#define BPG   (NBLK/NGRP)  // 8 arrivals per group counter
#define BAR_U32 1088       // per-barrier u32 stride (64 groups*16 + master + flag, padded)

// Hierarchical grid barrier: 64 padded group counters -> master -> flag.
// Pollers spin on the (read-only until set) flag line with s_sleep backoff.
// bar[] layout: bar[g*16] group g counter, bar[64*16] master, bar[64*16+8] flag.
__device__ __forceinline__ void grid_bar(unsigned* bar) {
    __syncthreads();
    if (threadIdx.x == 0) {
        const int g = blockIdx.x & (NGRP - 1);
        unsigned o = __hip_atomic_fetch_add(&bar[g * 16], 1u,
                        __ATOMIC_ACQ_REL, __HIP_MEMORY_SCOPE_AGENT);
        if (o == BPG - 1) {  // last arrival in group
            unsigned m = __hip_atomic_fetch_add(&bar[NGRP * 16], 1u,
                            __ATOMIC_ACQ_REL, __HIP_MEMORY_SCOPE_AGENT);
            if (m == NGRP - 1)
                __hip_atomic_store(&bar[NGRP * 16 + 8], 1u,
                        __ATOMIC_RELEASE, __HIP_MEMORY_SCOPE_AGENT);
        }
        while (!__hip_atomic_load(&bar[NGRP * 16 + 8],
                        __ATOMIC_RELAXED, __HIP_MEMORY_SCOPE_AGENT))
            __builtin_amdgcn_s_sleep(8);
        (void)__hip_atomic_load(&bar[NGRP * 16 + 8],
                        __ATOMIC_ACQUIRE, __HIP_MEMORY_SCOPE_AGENT);
    }
    __syncthreads();
}

// Block b owns outputs j in {4b..4b+3}. Wave w: jj = w&3, gate = w>>2,
// row = gate*H + 4b + jj  -> per gate the block reads 4 consecutive rows
// (32KB contiguous). Layer input vector and h0[l] live in LDS.
__global__ __launch_bounds__(NTHR, 8) void lstm_fused_kernel(
    const float* __restrict__ x,
    const float* __restrict__ w_ih,   // [L, 4H, H]
    const float* __restrict__ w_hh,   // [L, 4H, H]
    const float* __restrict__ b_ih,   // [L, 4H]
    const float* __restrict__ b_hh,   // [L, 4H]
    const float* __restrict__ h0,     // [L, H]
    const float* __restrict__ c0,     // [L, H]
    float* __restrict__ out,          // [H]
    float* __restrict__ hbuf,         // [H] layer-output ping buffer
    unsigned* __restrict__ bars)      // (NL-1) * BAR_U32, pre-zeroed
{
    __shared__ float s_v[HSZ];        // layer input vector
    __shared__ float s_h[HSZ];        // h0[l]
    __shared__ float s_g[4][4];       // [jj][gate]

    const int tid  = threadIdx.x;
    const int wave = tid >> 6;
    const int lane = tid & 63;
    const int jj   = wave & 3;
    const int gate = wave >> 2;
    const int j    = blockIdx.x * 4 + jj;
    const int row  = gate * HSZ + j;

    const float* cur = x;
    for (int l = 0; l < NL; ++l) {
        // stage input vector + h0[l] into LDS (float2 per thread)
        ((float2*)s_v)[tid] = ((const float2*)cur)[tid];
        ((float2*)s_h)[tid] = ((const float2*)(h0 + (size_t)l * HSZ))[tid];
        __syncthreads();

        const float4* __restrict__ wi =
            (const float4*)(w_ih + ((size_t)l * 4 * HSZ + row) * HSZ);
        const float4* __restrict__ wh =
            (const float4*)(w_hh + ((size_t)l * 4 * HSZ + row) * HSZ);
        const float4* __restrict__ v4 = (const float4*)s_v;
        const float4* __restrict__ h4 = (const float4*)s_h;

        float acc = 0.f;
        {   // pass 1: w_ih row . v   (8 loads in flight)
            float4 a0 = wi[lane      ], a1 = wi[lane +  64];
            float4 a2 = wi[lane + 128], a3 = wi[lane + 192];
            float4 a4 = wi[lane + 256], a5 = wi[lane + 320];
            float4 a6 = wi[lane + 384], a7 = wi[lane + 448];
            float4 v;
            v = v4[lane      ]; acc += a0.x*v.x + a0.y*v.y + a0.z*v.z + a0.w*v.w;
            v = v4[lane +  64]; acc += a1.x*v.x + a1.y*v.y + a1.z*v.z + a1.w*v.w;
            v = v4[lane + 128]; acc += a2.x*v.x + a2.y*v.y + a2.z*v.z + a2.w*v.w;
            v = v4[lane + 192]; acc += a3.x*v.x + a3.y*v.y + a3.z*v.z + a3.w*v.w;
            v = v4[lane + 256]; acc += a4.x*v.x + a4.y*v.y + a4.z*v.z + a4.w*v.w;
            v = v4[lane + 320]; acc += a5.x*v.x + a5.y*v.y + a5.z*v.z + a5.w*v.w;
            v = v4[lane + 384]; acc += a6.x*v.x + a6.y*v.y + a6.z*v.z + a6.w*v.w;
            v = v4[lane + 448]; acc += a7.x*v.x + a7.y*v.y + a7.z*v.z + a7.w*v.w;
        }
        {   // pass 2: w_hh row . h0[l]
            float4 a0 = wh[lane      ], a1 = wh[lane +  64];
            float4 a2 = wh[lane + 128], a3 = wh[lane + 192];
            float4 a4 = wh[lane + 256], a5 = wh[lane + 320];
            float4 a6 = wh[lane + 384], a7 = wh[lane + 448];
            float4 v;
            v = h4[lane      ]; acc += a0.x*v.x + a0.y*v.y + a0.z*v.z + a0.w*v.w;
            v = h4[lane +  64]; acc += a1.x*v.x + a1.y*v.y + a1.z*v.z + a1.w*v.w;
            v = h4[lane + 128]; acc += a2.x*v.x + a2.y*v.y + a2.z*v.z + a2.w*v.w;
            v = h4[lane + 192]; acc += a3.x*v.x + a3.y*v.y + a3.z*v.z + a3.w*v.w;
            v = h4[lane + 256]; acc += a4.x*v.x + a4.y*v.y + a4.z*v.z + a4.w*v.w;
            v = h4[lane + 320]; acc += a5.x*v.x + a5.y*v.y + a5.z*v.z + a5.w*v.w;
            v = h4[lane + 384]; acc += a6.x*v.x + a6.y*v.y + a6.z*v.z + a6.w*v.w;
            v = h4[lane + 448]; acc += a7.x*v.x + a7.y*v.y + a7.z*v.z + a7.w*v.w;
        }

        #pragma unroll
        for (int off = 32; off > 0; off >>= 1)
            acc += __shfl_down(acc, off, 64);

        if (lane == 0)
            s_g[jj][gate] = acc + b_ih[(size_t)l * 4 * HSZ + row]
                                + b_hh[(size_t)l * 4 * HSZ + row];
        __syncthreads();

        if (tid < 4) {  // cell math for this block's 4 outputs
            const int jo = blockIdx.x * 4 + tid;
            const float gi = s_g[tid][0];
            const float gf = s_g[tid][1];
            const float gg = s_g[tid][2];
            const float go = s_g[tid][3];
            const float si = 1.f / (1.f + __expf(-gi));
            const float sf = 1.f / (1.f + __expf(-gf));
            const float so = 1.f / (1.f + __expf(-go));
            const float tg = tanhf(gg);
            const float cn = sf * c0[(size_t)l * HSZ + jo] + si * tg;
            float h = so * tanhf(cn);
            if (l < NL - 1) {
                h = tanhf(h);
                hbuf[jo] = h;
            } else {
                out[jo] = h;
            }
        }

        if (l < NL - 1) {
            grid_bar(bars + (size_t)l * BAR_U32);
            cur = hbuf;
        }
    }
}

extern "C" void kernel_launch(void* const* d_in, const int* in_sizes, int n_in,
                              void* d_out, int out_size, void* d_ws, size_t ws_size,
                              hipStream_t stream) {
    const float* x    = (const float*)d_in[0];
    const float* w_ih = (const float*)d_in[1];
    const float* w_hh = (const float*)d_in[2];
    const float* b_ih = (const float*)d_in[3];
    const float* b_hh = (const float*)d_in[4];
    const float* h0   = (const float*)d_in[5];
    const float* c0   = (const float*)d_in[6];
    float* out = (float*)d_out;

    // ws layout: [bars: (NL-1)*BAR_U32 u32][hbuf: H floats]
    unsigned* bars = (unsigned*)d_ws;
    float* hbuf = (float*)((char*)d_ws + (size_t)(NL - 1) * BAR_U32 * 4);

    hipMemsetAsync(bars, 0, (size_t)(NL - 1) * BAR_U32 * 4, stream);
    lstm_fused_kernel<<<NBLK, NTHR, 0, stream>>>(
        x, w_ih, w_hh, b_ih, b_hh, h0, c0, out, hbuf, bars);
}